// Round 5
// baseline (130.764 us; speedup 1.0000x reference)
//
#include <hip/hip_runtime.h>

// NCC loss, fused single pass. R5: no raw-plane LDS (direct overlapped global
// loads + register W-slide), 256-thread blocks at 5 blocks/CU, 2-barrier
// single-buffered schedule, lgkmcnt-only fences.
// Volume [B=2][1][D=160][H=192][W=160] fp32. Window 9^3, zero-padded, /729.
// Tile TH=16 x TW=16, ZC=32 z-planes/chunk (NSTEP=40 planes touched).
// Superstep s (plane zt=z0-4+s):
//   P1: ISSUE(s+1): 6 global float4 -> regs  ||  C(s): H-axis 9-tap hsum->vsum
//   P2: BSTAGE(s+1): products+W-slide -> hsum ||  D(s): z-ring + cc epilogue
// hsum: written P2(s), read P1(s+1); WAR spans P1->P2 barrier. vsum: written
// P1(s), read P2(s); WAR spans P2->P1 barrier. Single-buffered, 2 barriers.

#define NB 2
#define ND 160
#define NH 192
#define NW 160
#define TH 16
#define TW 16
#define ZC 32
#define ZCH 5             // 5*32 = 160
#define NSTEP (ZC + 8)    // 40
#define NITER 45          // 5 blocks of 9 (static ring slots)
#define HR 24             // halo rows
#define HROWS 25
#define HSTR 20           // hsum row stride (16 used, mult of 4)
#define VROWS 17
#define VSTR 24           // vsum row stride: 24 -> D's b32 reads 2-way (free)
#define NTH 256

__device__ __forceinline__ float4 f4add(float4 a, float4 b) {
    return make_float4(a.x + b.x, a.y + b.y, a.z + b.z, a.w + b.w);
}
__device__ __forceinline__ float4 f4sub(float4 a, float4 b) {
    return make_float4(a.x - b.x, a.y - b.y, a.z - b.z, a.w - b.w);
}

// Publish fence: drain own LDS writes, raw barrier. No vmcnt drain.
__device__ __forceinline__ void barw() {
    asm volatile("s_waitcnt lgkmcnt(0)" ::: "memory");
    __builtin_amdgcn_s_barrier();
    asm volatile("" ::: "memory");
}

__global__ __launch_bounds__(NTH, 5) void ncc_main(
        const float* __restrict__ I, const float* __restrict__ J,
        double* __restrict__ gacc) {
    __shared__ float hsum[5][HROWS][HSTR];   // 10.0 KB
    __shared__ float vsum[5][VROWS][VSTR];   // 8.2 KB    total ~18.2 KB
    __shared__ double wred[4];

    const int tid = threadIdx.x;
    const int tx = tid & 15;
    const int ty = tid >> 4;      // for D when tid<256: ty 0..15

    const int tileW = blockIdx.x % (NW / TW);          // 0..9
    const int tileH = blockIdx.x / (NW / TW);          // 0..11
    const int w0 = tileW * TW;
    const int h0 = tileH * TH;
    const int z0 = blockIdx.y * ZC;
    const size_t volBase = (size_t)blockIdx.z * ND * NH * NW;

    // ---- BSTAGE decode: 96 threads = 24 rows x 4 output-quads ----
    const bool bs_on = (tid < 96);
    const int br = tid >> 2;                // 0..23
    const int bq = tid & 3;                 // 0..3
    const int bh = h0 - 4 + br;
    const bool h_ok = bs_on && bh >= 0 && bh < NH;
    bool wok[3];
    size_t goff[3];
#pragma unroll
    for (int kk = 0; kk < 3; ++kk) {
        const int w = w0 - 4 + 4 * (bq + kk);
        wok[kk] = (w >= 0) && (w <= NW - 4);
        goff[kk] = (size_t)bh * NW + w;
    }
    float4 gI[3], gJ[3];
#pragma unroll
    for (int kk = 0; kk < 3; ++kk) { gI[kk] = make_float4(0,0,0,0); gJ[kk] = gI[kk]; }

    // ---- C decode: tid 96..175 (disjoint from BSTAGE): 5f x 4cg x 4strips ----
    const bool c_on = (tid >= 96) && (tid < 176);
    const int cix = c_on ? (tid - 96) : 0;
    const int cf = cix >> 4;                // 0..4
    const int ccg = cix & 3;                // 0..3
    const int cstrip = (cix >> 2) & 3;      // 0..3
    const int cr0 = cstrip << 2;
    const int cc0 = ccg << 2;
    const float* csrc = &hsum[cf][cr0][cc0];
    float* cdst = &vsum[cf][cr0][cc0];

// issue 6 global float4 loads for plane t into regs (no wait)
#define ISSUE(t) do {                                                          \
    const int zt_ = z0 - 4 + (t);                                              \
    const bool zok_ = (zt_ >= 0) && (zt_ < ND);                                \
    const size_t zb_ = volBase + (size_t)zt_ * (NH * NW);                      \
    _Pragma("unroll") for (int kk = 0; kk < 3; ++kk) {                         \
        gI[kk] = make_float4(0.f, 0.f, 0.f, 0.f); gJ[kk] = gI[kk];             \
        if (h_ok && zok_ && wok[kk]) {                                         \
            gI[kk] = *(const float4*)(I + zb_ + goff[kk]);                     \
            gJ[kk] = *(const float4*)(J + zb_ + goff[kk]);                     \
        }                                                                      \
    }                                                                          \
} while (0)

// sliding 9-sum over 12-value window -> 4 outputs, write hsum[F][br][4*bq]
#define BSLIDE(EXPR, F) do {                                                   \
    float s_ = EXPR(0);                                                        \
    _Pragma("unroll") for (int k_ = 1; k_ < 9; ++k_) s_ += EXPR(k_);           \
    float o_[4]; o_[0] = s_;                                                   \
    _Pragma("unroll") for (int j_ = 1; j_ < 4; ++j_) {                         \
        s_ += EXPR(j_ + 8) - EXPR(j_ - 1); o_[j_] = s_; }                      \
    *(float4*)&hsum[F][br][4 * bq] = *(float4*)&o_[0];                         \
} while (0)
#define E_I(k)  pI[k]
#define E_J(k)  pJ[k]
#define E_I2(k) (pI[k] * pI[k])
#define E_J2(k) (pJ[k] * pJ[k])
#define E_IJ(k) (pI[k] * pJ[k])

// consume staged regs: products + W-axis sliding sums -> hsum (5 fields)
#define BSTW() do { if (bs_on) {                                               \
    float pI[12], pJ[12];                                                      \
    _Pragma("unroll") for (int kk = 0; kk < 3; ++kk) {                         \
        *(float4*)&pI[4 * kk] = gI[kk];                                        \
        *(float4*)&pJ[4 * kk] = gJ[kk];                                        \
    }                                                                          \
    BSLIDE(E_I, 0); BSLIDE(E_J, 1); BSLIDE(E_I2, 2);                           \
    BSLIDE(E_J2, 3); BSLIDE(E_IJ, 4);                                          \
} } while (0)

// H-axis 9-tap sliding sums: 4-row strip, keep only first 3 rows live
#define DO_C() do { if (c_on) {                                                \
    float4 r0v = *(const float4*)(csrc + 0 * HSTR);                            \
    float4 r1v = *(const float4*)(csrc + 1 * HSTR);                            \
    float4 r2v = *(const float4*)(csrc + 2 * HSTR);                            \
    float4 s4 = f4add(f4add(r0v, r1v), r2v);                                   \
    _Pragma("unroll") for (int k = 3; k < 9; ++k)                              \
        s4 = f4add(s4, *(const float4*)(csrc + k * HSTR));                     \
    *(float4*)(cdst + 0 * VSTR) = s4;                                          \
    s4 = f4sub(f4add(s4, *(const float4*)(csrc +  9 * HSTR)), r0v);            \
    *(float4*)(cdst + 1 * VSTR) = s4;                                          \
    s4 = f4sub(f4add(s4, *(const float4*)(csrc + 10 * HSTR)), r1v);            \
    *(float4*)(cdst + 2 * VSTR) = s4;                                          \
    s4 = f4sub(f4add(s4, *(const float4*)(csrc + 11 * HSTR)), r2v);            \
    *(float4*)(cdst + 3 * VSTR) = s4;                                          \
} } while (0)

    float ring[5][9];
    float acc[5];
#pragma unroll
    for (int f = 0; f < 5; ++f) {
        acc[f] = 0.f;
#pragma unroll
        for (int k = 0; k < 9; ++k) ring[f][k] = 0.f;
    }
    float partial = 0.f;

    // ---- prologue: plane 0 staged into hsum ----
    ISSUE(0);
    BSTW();
    barw();

#pragma unroll 1
    for (int ss = 0; ss < NITER; ss += 9) {
#pragma unroll
        for (int jj = 0; jj < 9; ++jj) {
            const int s = ss + jj;               // s % 9 == jj (static slot)
            if (s < NSTEP) {
                const bool more = (s + 1 < NSTEP);

                // ---- P1: ISSUE(s+1) || C(s) ----
                if (more) ISSUE(s + 1);
                DO_C();
                barw();

                // ---- P2: BSTAGE(s+1) || D(s) ----
                if (more) BSTW();
                {
#pragma unroll
                    for (int f = 0; f < 5; ++f) {
                        const float v = vsum[f][ty][tx];
                        acc[f] += v - ring[f][jj];
                        ring[f][jj] = v;
                    }
                    if (s >= 8) {
                        const float Is = acc[0], Js = acc[1];
                        const float I2 = acc[2], J2 = acc[3], IJ = acc[4];
                        const float inv = 1.0f / 729.0f;
                        const float uI = Is * inv, uJ = Js * inv;
                        const float cross = IJ - uJ * Is - uI * Js + uI * uJ * 729.0f;
                        const float Iv = I2 - 2.0f * uI * Is + uI * uI * 729.0f;
                        const float Jv = J2 - 2.0f * uJ * Js + uJ * uJ * 729.0f;
                        partial += cross * cross / (Iv * Jv + 1e-5f);
                    }
                }
                barw();
            }
        }
    }

    // ---------- reduction: wave shfl -> LDS -> one atomic per block ----------
    double dp = (double)partial;
#pragma unroll
    for (int off = 32; off > 0; off >>= 1)
        dp += __shfl_down(dp, off, 64);
    if ((tid & 63) == 0) wred[tid >> 6] = dp;
    __syncthreads();
    if (tid == 0) atomicAdd(gacc, wred[0] + wred[1] + wred[2] + wred[3]);
}

__global__ void ncc_fin(const double* __restrict__ gacc, float* __restrict__ out) {
    out[0] = (float)(-gacc[0] / (double)((long long)NB * ND * NH * NW));
}

extern "C" void kernel_launch(void* const* d_in, const int* in_sizes, int n_in,
                              void* d_out, int out_size, void* d_ws, size_t ws_size,
                              hipStream_t stream) {
    const float* I = (const float*)d_in[0];   // y_true
    const float* J = (const float*)d_in[1];   // y_pred
    double* ws = (double*)d_ws;

    hipMemsetAsync(d_ws, 0, sizeof(double), stream);   // graph-capture safe

    dim3 grid((NW / TW) * (NH / TH), ZCH, NB);         // 120 x 5 x 2 = 1200 blocks
    ncc_main<<<grid, NTH, 0, stream>>>(I, J, ws);
    ncc_fin<<<1, 1, 0, stream>>>(ws, (float*)d_out);
}

// Round 6
// 122.191 us; speedup vs baseline: 1.0702x; 1.0702x over previous
//
#include <hip/hip_runtime.h>

// NCC loss, fused single pass. R6 = R5 structure with the register-spill fix:
// __launch_bounds__(256,4) (VGPR cap 128, fits ~116 live regs; R5's (256,5)
// cap ~102 spilled the z-ring to scratch -> 198 MB HBM writes).
// Volume [B=2][1][D=160][H=192][W=160] fp32. Window 9^3, zero-padded, /729.
// Tile TH=16 x TW=16, ZC=32 z-planes/chunk (NSTEP=40 planes touched).
// Superstep s (plane zt=z0-4+s):
//   P1: ISSUE(s+1): 6 global float4 -> regs  ||  C(s): H-axis 9-tap hsum->vsum
//   P2: BSTAGE(s+1): products+W-slide -> hsum ||  D(s): z-ring + cc epilogue
// hsum: written P2(s), read P1(s+1); WAR spans P1->P2 barrier. vsum: written
// P1(s), read P2(s); WAR spans P2->P1 barrier. Single-buffered, 2 barriers.

#define NB 2
#define ND 160
#define NH 192
#define NW 160
#define TH 16
#define TW 16
#define ZC 32
#define ZCH 5             // 5*32 = 160
#define NSTEP (ZC + 8)    // 40
#define NITER 45          // 5 blocks of 9 (static ring slots)
#define HR 24             // halo rows
#define HROWS 25
#define HSTR 20           // hsum row stride (16 used, mult of 4)
#define VROWS 17
#define VSTR 24           // vsum row stride
#define NTH 256

__device__ __forceinline__ float4 f4add(float4 a, float4 b) {
    return make_float4(a.x + b.x, a.y + b.y, a.z + b.z, a.w + b.w);
}
__device__ __forceinline__ float4 f4sub(float4 a, float4 b) {
    return make_float4(a.x - b.x, a.y - b.y, a.z - b.z, a.w - b.w);
}

// Publish fence: drain own LDS writes, raw barrier. No vmcnt drain.
__device__ __forceinline__ void barw() {
    asm volatile("s_waitcnt lgkmcnt(0)" ::: "memory");
    __builtin_amdgcn_s_barrier();
    asm volatile("" ::: "memory");
}

__global__ __launch_bounds__(NTH, 4) void ncc_main(
        const float* __restrict__ I, const float* __restrict__ J,
        double* __restrict__ gacc) {
    __shared__ float hsum[5][HROWS][HSTR];   // 10.0 KB
    __shared__ float vsum[5][VROWS][VSTR];   // 8.2 KB    total ~18.2 KB
    __shared__ double wred[4];

    const int tid = threadIdx.x;
    const int tx = tid & 15;
    const int ty = tid >> 4;      // for D: ty 0..15

    const int tileW = blockIdx.x % (NW / TW);          // 0..9
    const int tileH = blockIdx.x / (NW / TW);          // 0..11
    const int w0 = tileW * TW;
    const int h0 = tileH * TH;
    const int z0 = blockIdx.y * ZC;
    const size_t volBase = (size_t)blockIdx.z * ND * NH * NW;

    // ---- BSTAGE decode: 96 threads = 24 rows x 4 output-quads ----
    const bool bs_on = (tid < 96);
    const int br = tid >> 2;                // 0..23
    const int bq = tid & 3;                 // 0..3
    const int bh = h0 - 4 + br;
    const bool h_ok = bs_on && bh >= 0 && bh < NH;
    bool wok[3];
    size_t goff[3];
#pragma unroll
    for (int kk = 0; kk < 3; ++kk) {
        const int w = w0 - 4 + 4 * (bq + kk);
        wok[kk] = (w >= 0) && (w <= NW - 4);
        goff[kk] = (size_t)bh * NW + w;
    }
    float4 gI[3], gJ[3];
#pragma unroll
    for (int kk = 0; kk < 3; ++kk) { gI[kk] = make_float4(0,0,0,0); gJ[kk] = gI[kk]; }

    // ---- C decode: tid 96..175 (disjoint from BSTAGE): 5f x 4cg x 4strips ----
    const bool c_on = (tid >= 96) && (tid < 176);
    const int cix = c_on ? (tid - 96) : 0;
    const int cf = cix >> 4;                // 0..4
    const int ccg = cix & 3;                // 0..3
    const int cstrip = (cix >> 2) & 3;      // 0..3
    const int cr0 = cstrip << 2;
    const int cc0 = ccg << 2;
    const float* csrc = &hsum[cf][cr0][cc0];
    float* cdst = &vsum[cf][cr0][cc0];

// issue 6 global float4 loads for plane t into regs (no wait)
#define ISSUE(t) do {                                                          \
    const int zt_ = z0 - 4 + (t);                                              \
    const bool zok_ = (zt_ >= 0) && (zt_ < ND);                                \
    const size_t zb_ = volBase + (size_t)zt_ * (NH * NW);                      \
    _Pragma("unroll") for (int kk = 0; kk < 3; ++kk) {                         \
        gI[kk] = make_float4(0.f, 0.f, 0.f, 0.f); gJ[kk] = gI[kk];             \
        if (h_ok && zok_ && wok[kk]) {                                         \
            gI[kk] = *(const float4*)(I + zb_ + goff[kk]);                     \
            gJ[kk] = *(const float4*)(J + zb_ + goff[kk]);                     \
        }                                                                      \
    }                                                                          \
} while (0)

// sliding 9-sum over 12-value window -> 4 outputs, write hsum[F][br][4*bq]
#define BSLIDE(EXPR, F) do {                                                   \
    float s_ = EXPR(0);                                                        \
    _Pragma("unroll") for (int k_ = 1; k_ < 9; ++k_) s_ += EXPR(k_);           \
    float o_[4]; o_[0] = s_;                                                   \
    _Pragma("unroll") for (int j_ = 1; j_ < 4; ++j_) {                         \
        s_ += EXPR(j_ + 8) - EXPR(j_ - 1); o_[j_] = s_; }                      \
    *(float4*)&hsum[F][br][4 * bq] = *(float4*)&o_[0];                         \
} while (0)
#define E_I(k)  pI[k]
#define E_J(k)  pJ[k]
#define E_I2(k) (pI[k] * pI[k])
#define E_J2(k) (pJ[k] * pJ[k])
#define E_IJ(k) (pI[k] * pJ[k])

// consume staged regs: products + W-axis sliding sums -> hsum (5 fields)
#define BSTW() do { if (bs_on) {                                               \
    float pI[12], pJ[12];                                                      \
    _Pragma("unroll") for (int kk = 0; kk < 3; ++kk) {                         \
        *(float4*)&pI[4 * kk] = gI[kk];                                        \
        *(float4*)&pJ[4 * kk] = gJ[kk];                                        \
    }                                                                          \
    BSLIDE(E_I, 0); BSLIDE(E_J, 1); BSLIDE(E_I2, 2);                           \
    BSLIDE(E_J2, 3); BSLIDE(E_IJ, 4);                                          \
} } while (0)

// H-axis 9-tap sliding sums: 4-row strip
#define DO_C() do { if (c_on) {                                                \
    float4 r0v = *(const float4*)(csrc + 0 * HSTR);                            \
    float4 r1v = *(const float4*)(csrc + 1 * HSTR);                            \
    float4 r2v = *(const float4*)(csrc + 2 * HSTR);                            \
    float4 s4 = f4add(f4add(r0v, r1v), r2v);                                   \
    _Pragma("unroll") for (int k = 3; k < 9; ++k)                              \
        s4 = f4add(s4, *(const float4*)(csrc + k * HSTR));                     \
    *(float4*)(cdst + 0 * VSTR) = s4;                                          \
    s4 = f4sub(f4add(s4, *(const float4*)(csrc +  9 * HSTR)), r0v);            \
    *(float4*)(cdst + 1 * VSTR) = s4;                                          \
    s4 = f4sub(f4add(s4, *(const float4*)(csrc + 10 * HSTR)), r1v);            \
    *(float4*)(cdst + 2 * VSTR) = s4;                                          \
    s4 = f4sub(f4add(s4, *(const float4*)(csrc + 11 * HSTR)), r2v);            \
    *(float4*)(cdst + 3 * VSTR) = s4;                                          \
} } while (0)

    float ring[5][9];
    float acc[5];
#pragma unroll
    for (int f = 0; f < 5; ++f) {
        acc[f] = 0.f;
#pragma unroll
        for (int k = 0; k < 9; ++k) ring[f][k] = 0.f;
    }
    float partial = 0.f;

    // ---- prologue: plane 0 staged into hsum ----
    ISSUE(0);
    BSTW();
    barw();

#pragma unroll 1
    for (int ss = 0; ss < NITER; ss += 9) {
#pragma unroll
        for (int jj = 0; jj < 9; ++jj) {
            const int s = ss + jj;               // s % 9 == jj (static slot)
            if (s < NSTEP) {
                const bool more = (s + 1 < NSTEP);

                // ---- P1: ISSUE(s+1) || C(s) ----
                if (more) ISSUE(s + 1);
                DO_C();
                barw();

                // ---- P2: BSTAGE(s+1) || D(s) ----
                if (more) BSTW();
                {
#pragma unroll
                    for (int f = 0; f < 5; ++f) {
                        const float v = vsum[f][ty][tx];
                        acc[f] += v - ring[f][jj];
                        ring[f][jj] = v;
                    }
                    if (s >= 8) {
                        const float Is = acc[0], Js = acc[1];
                        const float I2 = acc[2], J2 = acc[3], IJ = acc[4];
                        const float inv = 1.0f / 729.0f;
                        const float uI = Is * inv, uJ = Js * inv;
                        const float cross = IJ - uJ * Is - uI * Js + uI * uJ * 729.0f;
                        const float Iv = I2 - 2.0f * uI * Is + uI * uI * 729.0f;
                        const float Jv = J2 - 2.0f * uJ * Js + uJ * uJ * 729.0f;
                        partial += cross * cross / (Iv * Jv + 1e-5f);
                    }
                }
                barw();
            }
        }
    }

    // ---------- reduction: wave shfl -> LDS -> one atomic per block ----------
    double dp = (double)partial;
#pragma unroll
    for (int off = 32; off > 0; off >>= 1)
        dp += __shfl_down(dp, off, 64);
    if ((tid & 63) == 0) wred[tid >> 6] = dp;
    __syncthreads();
    if (tid == 0) atomicAdd(gacc, wred[0] + wred[1] + wred[2] + wred[3]);
}

__global__ void ncc_fin(const double* __restrict__ gacc, float* __restrict__ out) {
    out[0] = (float)(-gacc[0] / (double)((long long)NB * ND * NH * NW));
}

extern "C" void kernel_launch(void* const* d_in, const int* in_sizes, int n_in,
                              void* d_out, int out_size, void* d_ws, size_t ws_size,
                              hipStream_t stream) {
    const float* I = (const float*)d_in[0];   // y_true
    const float* J = (const float*)d_in[1];   // y_pred
    double* ws = (double*)d_ws;

    hipMemsetAsync(d_ws, 0, sizeof(double), stream);   // graph-capture safe

    dim3 grid((NW / TW) * (NH / TH), ZCH, NB);         // 120 x 5 x 2 = 1200 blocks
    ncc_main<<<grid, NTH, 0, stream>>>(I, J, ws);
    ncc_fin<<<1, 1, 0, stream>>>(ws, (float*)d_out);
}

// Round 7
// 122.041 us; speedup vs baseline: 1.0715x; 1.0012x over previous
//
#include <hip/hip_runtime.h>

// NCC loss, fused single pass. R7: ONE barrier per plane via parity
// double-buffered hsum/vsum; long per-thread streams; spill fix via
// single-arg __launch_bounds__ (R6's (256,4) cap=128 spilled the ring).
// Volume [B=2][1][D=160][H=192][W=160] fp32. Window 9^3, zero-padded, /729.
// Tile TH=16 x TW=16, ZC=32 z-planes/chunk, planes i=0..39 (zt=z0-4+i).
// Superstep t (t=0..41), one barrier at end:
//   BSTW(t):  consume regs of ISSUE(t) -> products+W-slide -> hsum[t&1]
//   ISSUE(t+1): 6 global float4 -> regs (covered by a full superstep)
//   C(t-1):  H-axis 9-tap hsum[(t-1)&1] -> vsum[(t-1)&1]
//   D(t-2):  z-ring + cc from vsum[t&1]
// Hazard audit (all span >=1 barrier):
//   BSTW(t) w hsum[p]  vs C(t-1) r hsum[p^1]          : disjoint
//   C(t-1) r hsum[p^1] vs BSTW(t+1) w hsum[p^1]       : 1 barrier (WAR)
//   C(t-1) w vsum[p^1] vs D(t-2) r vsum[p]            : disjoint
//   D(t-2) r vsum[p]   vs C(t) w vsum[p] (next step)  : 1 barrier (WAR)
//   BSTW(t) -> C(t) / C(t-1) -> D(t-1) (next step)    : 1 barrier (RAW)

#define NB 2
#define ND 160
#define NH 192
#define NW 160
#define TH 16
#define TW 16
#define ZC 32
#define ZCH 5              // 5*32 = 160
#define NSTEP (ZC + 8)     // 40 planes
#define TSUP (NSTEP + 2)   // 42 supersteps
#define NITER 45           // 5 blocks of 9 (static ring slots)
#define HROWS 25           // 24 used + pad
#define HSTR 20
#define VROWS 17           // 16 used + pad
#define VSTR 24
#define NTH 256
#define HFSTR (HROWS * HSTR)   // hsum field stride (words)
#define VFSTR (VROWS * VSTR)   // vsum field stride

__device__ __forceinline__ float4 f4add(float4 a, float4 b) {
    return make_float4(a.x + b.x, a.y + b.y, a.z + b.z, a.w + b.w);
}
__device__ __forceinline__ float4 f4sub(float4 a, float4 b) {
    return make_float4(a.x - b.x, a.y - b.y, a.z - b.z, a.w - b.w);
}

// Publish fence: drain own LDS writes, raw barrier. No vmcnt drain --
// in-flight global loads keep flying across the sync.
__device__ __forceinline__ void barw() {
    asm volatile("s_waitcnt lgkmcnt(0)" ::: "memory");
    __builtin_amdgcn_s_barrier();
    asm volatile("" ::: "memory");
}

__global__ __launch_bounds__(NTH) void ncc_main(
        const float* __restrict__ I, const float* __restrict__ J,
        double* __restrict__ gacc) {
    __shared__ float hsum[2][5][HROWS][HSTR];   // 20.0 KB
    __shared__ float vsum[2][5][VROWS][VSTR];   // 16.3 KB   total 36.3 KB
    __shared__ double wred[4];

    const int tid = threadIdx.x;
    const int tx = tid & 15;
    const int ty = tid >> 4;

    const int tileW = blockIdx.x % (NW / TW);          // 0..9
    const int tileH = blockIdx.x / (NW / TW);          // 0..11
    const int w0 = tileW * TW;
    const int h0 = tileH * TH;
    const int z0 = blockIdx.y * ZC;
    const size_t volBase = (size_t)blockIdx.z * ND * NH * NW;

    // ---- BSTAGE/ISSUE decode: 96 threads = 24 halo rows x 4 output-quads ----
    const bool bs_on = (tid < 96);
    const int br = tid >> 2;                // 0..23
    const int bq = tid & 3;                 // 0..3
    const int bh = h0 - 4 + br;
    const bool h_ok = bs_on && bh >= 0 && bh < NH;
    bool wok[3];
    int goff[3];
#pragma unroll
    for (int kk = 0; kk < 3; ++kk) {
        const int w = w0 - 4 + 4 * (bq + kk);
        wok[kk] = (w >= 0) && (w <= NW - 4);
        goff[kk] = bh * NW + w;
    }
    float4 gI[3], gJ[3];
#pragma unroll
    for (int kk = 0; kk < 3; ++kk) { gI[kk] = make_float4(0,0,0,0); gJ[kk] = gI[kk]; }

    // ---- C decode: tid 96..175 (disjoint from BSTAGE): 5f x 4cg x 4strips ----
    const bool c_on = (tid >= 96) && (tid < 176);
    const int cix = c_on ? (tid - 96) : 0;
    const int cf = cix >> 4;                // 0..4
    const int ccg = cix & 3;                // 0..3
    const int cstrip = (cix >> 2) & 3;      // 0..3
    const int cr0 = cstrip << 2;
    const int cc0 = ccg << 2;
    const int c_off = cf * HFSTR + cr0 * HSTR + cc0;   // within hsum[p]
    const int v_off = cf * VFSTR + cr0 * VSTR + cc0;   // within vsum[p]

// issue 6 global float4 loads for plane t into regs (no wait)
#define ISSUE(t) do {                                                          \
    const int zt_ = z0 - 4 + (t);                                              \
    const bool zok_ = (zt_ >= 0) && (zt_ < ND);                                \
    const size_t zb_ = volBase + (size_t)zt_ * (NH * NW);                      \
    _Pragma("unroll") for (int kk = 0; kk < 3; ++kk) {                         \
        gI[kk] = make_float4(0.f, 0.f, 0.f, 0.f); gJ[kk] = gI[kk];             \
        if (h_ok && zok_ && wok[kk]) {                                         \
            gI[kk] = *(const float4*)(I + zb_ + goff[kk]);                     \
            gJ[kk] = *(const float4*)(J + zb_ + goff[kk]);                     \
        }                                                                      \
    }                                                                          \
} while (0)

// sliding 9-sum over 12-value window -> 4 outputs into bdst_ + F*HFSTR
#define BSLIDE(EXPR, F, bdst_) do {                                            \
    float s_ = EXPR(0);                                                        \
    _Pragma("unroll") for (int k_ = 1; k_ < 9; ++k_) s_ += EXPR(k_);           \
    float o_[4]; o_[0] = s_;                                                   \
    _Pragma("unroll") for (int j_ = 1; j_ < 4; ++j_) {                         \
        s_ += EXPR(j_ + 8) - EXPR(j_ - 1); o_[j_] = s_; }                      \
    *(float4*)((bdst_) + (F) * HFSTR) = *(float4*)&o_[0];                      \
} while (0)
#define E_I(k)  pI[k]
#define E_J(k)  pJ[k]
#define E_I2(k) (pI[k] * pI[k])
#define E_J2(k) (pJ[k] * pJ[k])
#define E_IJ(k) (pI[k] * pJ[k])

// consume staged regs: products + W-axis sliding sums -> hsum[P] (5 fields)
#define BSTW(P) do { if (bs_on) {                                              \
    float pI[12], pJ[12];                                                      \
    _Pragma("unroll") for (int kk = 0; kk < 3; ++kk) {                         \
        *(float4*)&pI[4 * kk] = gI[kk];                                        \
        *(float4*)&pJ[4 * kk] = gJ[kk];                                        \
    }                                                                          \
    float* bdst_ = &hsum[P][0][br][4 * bq];                                    \
    BSLIDE(E_I, 0, bdst_); BSLIDE(E_J, 1, bdst_); BSLIDE(E_I2, 2, bdst_);      \
    BSLIDE(E_J2, 3, bdst_); BSLIDE(E_IJ, 4, bdst_);                            \
} } while (0)

// H-axis 9-tap sliding sums: 4-row strip, hsum[P] -> vsum[P]
#define DO_C(P) do { if (c_on) {                                               \
    const float* csrc = &hsum[P][0][0][0] + c_off;                             \
    float* cdst = &vsum[P][0][0][0] + v_off;                                   \
    float4 r0v = *(const float4*)(csrc + 0 * HSTR);                            \
    float4 r1v = *(const float4*)(csrc + 1 * HSTR);                            \
    float4 r2v = *(const float4*)(csrc + 2 * HSTR);                            \
    float4 s4 = f4add(f4add(r0v, r1v), r2v);                                   \
    _Pragma("unroll") for (int k = 3; k < 9; ++k)                              \
        s4 = f4add(s4, *(const float4*)(csrc + k * HSTR));                     \
    *(float4*)(cdst + 0 * VSTR) = s4;                                          \
    s4 = f4sub(f4add(s4, *(const float4*)(csrc +  9 * HSTR)), r0v);            \
    *(float4*)(cdst + 1 * VSTR) = s4;                                          \
    s4 = f4sub(f4add(s4, *(const float4*)(csrc + 10 * HSTR)), r1v);            \
    *(float4*)(cdst + 2 * VSTR) = s4;                                          \
    s4 = f4sub(f4add(s4, *(const float4*)(csrc + 11 * HSTR)), r2v);            \
    *(float4*)(cdst + 3 * VSTR) = s4;                                          \
} } while (0)

    float ring[5][9];
    float acc[5];
#pragma unroll
    for (int f = 0; f < 5; ++f) {
        acc[f] = 0.f;
#pragma unroll
        for (int k = 0; k < 9; ++k) ring[f][k] = 0.f;
    }
    float partial = 0.f;

    // ---- prologue: issue plane 0 loads ----
    ISSUE(0);

#pragma unroll 1
    for (int tt = 0; tt < NITER; tt += 9) {
#pragma unroll
        for (int jj = 0; jj < 9; ++jj) {
            const int t = tt + jj;
            if (t < TSUP) {
                const int pB = t & 1;                 // hsum buf for BSTW(t)
                const bool doB = (t <= NSTEP - 1);
                const bool doI = (t + 1 <= NSTEP - 1);
                const bool doC = (t >= 1);            // t <= NSTEP holds: t<=41
                const bool doD = (t >= 2);

                if (doB) BSTW(pB);
                if (doI) ISSUE(t + 1);
                if (doC) DO_C(pB ^ 1);

                if (doD) {
                    const int slot = (jj + 7) % 9;    // (t-2) % 9, static
                    const float* vbase = &vsum[pB][0][ty][tx];
#pragma unroll
                    for (int f = 0; f < 5; ++f) {
                        const float v = vbase[f * VFSTR];
                        acc[f] += v - ring[f][slot];
                        ring[f][slot] = v;
                    }
                    if (t - 2 >= 8) {
                        const float Is = acc[0], Js = acc[1];
                        const float I2 = acc[2], J2 = acc[3], IJ = acc[4];
                        const float inv = 1.0f / 729.0f;
                        const float uI = Is * inv, uJ = Js * inv;
                        const float cross = IJ - uJ * Is - uI * Js + uI * uJ * 729.0f;
                        const float Iv = I2 - 2.0f * uI * Is + uI * uI * 729.0f;
                        const float Jv = J2 - 2.0f * uJ * Js + uJ * uJ * 729.0f;
                        partial += cross * cross / (Iv * Jv + 1e-5f);
                    }
                }
                barw();
            }
        }
    }

    // ---------- reduction: wave shfl -> LDS -> one atomic per block ----------
    double dp = (double)partial;
#pragma unroll
    for (int off = 32; off > 0; off >>= 1)
        dp += __shfl_down(dp, off, 64);
    if ((tid & 63) == 0) wred[tid >> 6] = dp;
    __syncthreads();
    if (tid == 0) atomicAdd(gacc, wred[0] + wred[1] + wred[2] + wred[3]);
}

__global__ void ncc_fin(const double* __restrict__ gacc, float* __restrict__ out) {
    out[0] = (float)(-gacc[0] / (double)((long long)NB * ND * NH * NW));
}

extern "C" void kernel_launch(void* const* d_in, const int* in_sizes, int n_in,
                              void* d_out, int out_size, void* d_ws, size_t ws_size,
                              hipStream_t stream) {
    const float* I = (const float*)d_in[0];   // y_true
    const float* J = (const float*)d_in[1];   // y_pred
    double* ws = (double*)d_ws;

    hipMemsetAsync(d_ws, 0, sizeof(double), stream);   // graph-capture safe

    dim3 grid((NW / TW) * (NH / TH), ZCH, NB);         // 120 x 5 x 2 = 1200 blocks
    ncc_main<<<grid, NTH, 0, stream>>>(I, J, ws);
    ncc_fin<<<1, 1, 0, stream>>>(ws, (float*)d_out);
}

// Round 8
// 111.630 us; speedup vs baseline: 1.1714x; 1.0933x over previous
//
#include <hip/hip_runtime.h>

// NCC loss, fused single pass. R8: occupancy attack — ZC=16 (2400 blocks,
// 9.4/CU), LDS shrunk to 16.4 KB (9 blocks/CU), 2-barrier single-buffered
// schedule (R5/R6-validated), plain launch_bounds (R7-proven spill-free),
// raw s_barrier + lgkmcnt-only fences, 6-load register prefetch.
// Volume [B=2][1][D=160][H=192][W=160] fp32. Window 9^3, zero-padded, /729.
// Tile TH=16 x TW=16, ZC=16 z-planes/chunk (NSTEP=24 planes touched).
// Superstep s (plane zt=z0-4+s):
//   P1: ISSUE(s+1): 6 global float4 -> regs  ||  C(s): H-axis 9-tap hsum->vsum
//   P2: BSTW(s+1): products+W-slide -> hsum  ||  D(s): z-ring + cc epilogue
// Hazards (single-buffered, 2 barriers):
//   BSTW(s) w hsum -> C(s) r hsum   : RAW across P2->P1 barrier
//   C(s) r hsum -> BSTW(s+1) w hsum : WAR across P1->P2 barrier
//   C(s) w vsum -> D(s) r vsum      : RAW across P1->P2 barrier
//   D(s) r vsum -> C(s+1) w vsum    : WAR across P2->P1 barrier

#define NB 2
#define ND 160
#define NH 192
#define NW 160
#define TH 16
#define TW 16
#define ZC 16
#define ZCH 10             // 10*16 = 160
#define NSTEP (ZC + 8)     // 24 planes touched per chunk
#define NITER 27           // 3 blocks of 9 (static ring slots)
#define HROWS 25           // 24 used + 1 pad
#define HSTR 20            // 16 used + 4
#define VROWS 16
#define VSTR 20
#define NTH 256

__device__ __forceinline__ float4 f4add(float4 a, float4 b) {
    return make_float4(a.x + b.x, a.y + b.y, a.z + b.z, a.w + b.w);
}
__device__ __forceinline__ float4 f4sub(float4 a, float4 b) {
    return make_float4(a.x - b.x, a.y - b.y, a.z - b.z, a.w - b.w);
}

// Publish fence: drain own LDS writes, raw barrier. No vmcnt drain --
// in-flight global loads keep flying across the sync.
__device__ __forceinline__ void barw() {
    asm volatile("s_waitcnt lgkmcnt(0)" ::: "memory");
    __builtin_amdgcn_s_barrier();
    asm volatile("" ::: "memory");
}

__global__ __launch_bounds__(NTH) void ncc_main(
        const float* __restrict__ I, const float* __restrict__ J,
        double* __restrict__ gacc) {
    __shared__ float hsum[5][HROWS][HSTR];   // 10.0 KB
    __shared__ float vsum[5][VROWS][VSTR];   // 6.4 KB    total 16.4 KB
    __shared__ double wred[4];

    const int tid = threadIdx.x;
    const int tx = tid & 15;
    const int ty = tid >> 4;      // D: ty 0..15

    const int tileW = blockIdx.x % (NW / TW);          // 0..9
    const int tileH = blockIdx.x / (NW / TW);          // 0..11
    const int w0 = tileW * TW;
    const int h0 = tileH * TH;
    const int z0 = blockIdx.y * ZC;
    const size_t volBase = (size_t)blockIdx.z * ND * NH * NW;

    // ---- BSTW/ISSUE decode: 96 threads = 24 halo rows x 4 output-quads ----
    const bool bs_on = (tid < 96);
    const int br = tid >> 2;                // 0..23
    const int bq = tid & 3;                 // 0..3
    const int bh = h0 - 4 + br;
    const bool h_ok = bs_on && bh >= 0 && bh < NH;
    bool wok[3];
    int goff[3];
#pragma unroll
    for (int kk = 0; kk < 3; ++kk) {
        const int w = w0 - 4 + 4 * (bq + kk);
        wok[kk] = (w >= 0) && (w <= NW - 4);
        goff[kk] = bh * NW + w;
    }
    float4 gI[3], gJ[3];
#pragma unroll
    for (int kk = 0; kk < 3; ++kk) { gI[kk] = make_float4(0,0,0,0); gJ[kk] = gI[kk]; }

    // ---- C decode: tid 96..175 (disjoint from BSTW): 5f x 4cg x 4strips ----
    const bool c_on = (tid >= 96) && (tid < 176);
    const int cix = c_on ? (tid - 96) : 0;
    const int cf = cix >> 4;                // 0..4
    const int ccg = cix & 3;                // 0..3
    const int cstrip = (cix >> 2) & 3;      // 0..3
    const int cr0 = cstrip << 2;
    const int cc0 = ccg << 2;
    const float* csrc = &hsum[cf][cr0][cc0];
    float* cdst = &vsum[cf][cr0][cc0];

// issue 6 global float4 loads for plane t into regs (no wait)
#define ISSUE(t) do {                                                          \
    const int zt_ = z0 - 4 + (t);                                              \
    const bool zok_ = (zt_ >= 0) && (zt_ < ND);                                \
    const size_t zb_ = volBase + (size_t)zt_ * (NH * NW);                      \
    _Pragma("unroll") for (int kk = 0; kk < 3; ++kk) {                         \
        gI[kk] = make_float4(0.f, 0.f, 0.f, 0.f); gJ[kk] = gI[kk];             \
        if (h_ok && zok_ && wok[kk]) {                                         \
            gI[kk] = *(const float4*)(I + zb_ + goff[kk]);                     \
            gJ[kk] = *(const float4*)(J + zb_ + goff[kk]);                     \
        }                                                                      \
    }                                                                          \
} while (0)

// sliding 9-sum over 12-value window -> 4 outputs, write hsum[F][br][4*bq]
#define BSLIDE(EXPR, F) do {                                                   \
    float s_ = EXPR(0);                                                        \
    _Pragma("unroll") for (int k_ = 1; k_ < 9; ++k_) s_ += EXPR(k_);           \
    float o_[4]; o_[0] = s_;                                                   \
    _Pragma("unroll") for (int j_ = 1; j_ < 4; ++j_) {                         \
        s_ += EXPR(j_ + 8) - EXPR(j_ - 1); o_[j_] = s_; }                      \
    *(float4*)&hsum[F][br][4 * bq] = *(float4*)&o_[0];                         \
} while (0)
#define E_I(k)  pI[k]
#define E_J(k)  pJ[k]
#define E_I2(k) (pI[k] * pI[k])
#define E_J2(k) (pJ[k] * pJ[k])
#define E_IJ(k) (pI[k] * pJ[k])

// consume staged regs: products + W-axis sliding sums -> hsum (5 fields)
#define BSTW() do { if (bs_on) {                                               \
    float pI[12], pJ[12];                                                      \
    _Pragma("unroll") for (int kk = 0; kk < 3; ++kk) {                         \
        *(float4*)&pI[4 * kk] = gI[kk];                                        \
        *(float4*)&pJ[4 * kk] = gJ[kk];                                        \
    }                                                                          \
    BSLIDE(E_I, 0); BSLIDE(E_J, 1); BSLIDE(E_I2, 2);                           \
    BSLIDE(E_J2, 3); BSLIDE(E_IJ, 4);                                          \
} } while (0)

// H-axis 9-tap sliding sums: 4-row strip, hsum -> vsum
#define DO_C() do { if (c_on) {                                                \
    float4 r0v = *(const float4*)(csrc + 0 * HSTR);                            \
    float4 r1v = *(const float4*)(csrc + 1 * HSTR);                            \
    float4 r2v = *(const float4*)(csrc + 2 * HSTR);                            \
    float4 s4 = f4add(f4add(r0v, r1v), r2v);                                   \
    _Pragma("unroll") for (int k = 3; k < 9; ++k)                              \
        s4 = f4add(s4, *(const float4*)(csrc + k * HSTR));                     \
    *(float4*)(cdst + 0 * VSTR) = s4;                                          \
    s4 = f4sub(f4add(s4, *(const float4*)(csrc +  9 * HSTR)), r0v);            \
    *(float4*)(cdst + 1 * VSTR) = s4;                                          \
    s4 = f4sub(f4add(s4, *(const float4*)(csrc + 10 * HSTR)), r1v);            \
    *(float4*)(cdst + 2 * VSTR) = s4;                                          \
    s4 = f4sub(f4add(s4, *(const float4*)(csrc + 11 * HSTR)), r2v);            \
    *(float4*)(cdst + 3 * VSTR) = s4;                                          \
} } while (0)

    float ring[5][9];
    float acc[5];
#pragma unroll
    for (int f = 0; f < 5; ++f) {
        acc[f] = 0.f;
#pragma unroll
        for (int k = 0; k < 9; ++k) ring[f][k] = 0.f;
    }
    float partial = 0.f;

    // ---- prologue: plane 0 staged into hsum ----
    ISSUE(0);
    BSTW();
    barw();

#pragma unroll 1
    for (int ss = 0; ss < NITER; ss += 9) {
#pragma unroll
        for (int jj = 0; jj < 9; ++jj) {
            const int s = ss + jj;               // s % 9 == jj (static slot)
            if (s < NSTEP) {
                const bool more = (s + 1 < NSTEP);

                // ---- P1: ISSUE(s+1) || C(s) ----
                if (more) ISSUE(s + 1);
                DO_C();
                barw();

                // ---- P2: BSTW(s+1) || D(s) ----
                if (more) BSTW();
                {
#pragma unroll
                    for (int f = 0; f < 5; ++f) {
                        const float v = vsum[f][ty][tx];
                        acc[f] += v - ring[f][jj];
                        ring[f][jj] = v;
                    }
                    if (s >= 8) {
                        const float Is = acc[0], Js = acc[1];
                        const float I2 = acc[2], J2 = acc[3], IJ = acc[4];
                        const float inv = 1.0f / 729.0f;
                        const float uI = Is * inv, uJ = Js * inv;
                        const float cross = IJ - uJ * Is - uI * Js + uI * uJ * 729.0f;
                        const float Iv = I2 - 2.0f * uI * Is + uI * uI * 729.0f;
                        const float Jv = J2 - 2.0f * uJ * Js + uJ * uJ * 729.0f;
                        partial += cross * cross / (Iv * Jv + 1e-5f);
                    }
                }
                barw();
            }
        }
    }

    // ---------- reduction: wave shfl -> LDS -> one atomic per block ----------
    double dp = (double)partial;
#pragma unroll
    for (int off = 32; off > 0; off >>= 1)
        dp += __shfl_down(dp, off, 64);
    if ((tid & 63) == 0) wred[tid >> 6] = dp;
    __syncthreads();
    if (tid == 0) atomicAdd(gacc, wred[0] + wred[1] + wred[2] + wred[3]);
}

__global__ void ncc_fin(const double* __restrict__ gacc, float* __restrict__ out) {
    out[0] = (float)(-gacc[0] / (double)((long long)NB * ND * NH * NW));
}

extern "C" void kernel_launch(void* const* d_in, const int* in_sizes, int n_in,
                              void* d_out, int out_size, void* d_ws, size_t ws_size,
                              hipStream_t stream) {
    const float* I = (const float*)d_in[0];   // y_true
    const float* J = (const float*)d_in[1];   // y_pred
    double* ws = (double*)d_ws;

    hipMemsetAsync(d_ws, 0, sizeof(double), stream);   // graph-capture safe

    dim3 grid((NW / TW) * (NH / TH), ZCH, NB);         // 120 x 10 x 2 = 2400 blocks
    ncc_main<<<grid, NTH, 0, stream>>>(I, J, ws);
    ncc_fin<<<1, 1, 0, stream>>>(ws, (float*)d_out);
}

// Round 9
// 109.340 us; speedup vs baseline: 1.1959x; 1.0209x over previous
//
#include <hip/hip_runtime.h>

// NCC loss, fused single pass. R9 = R8 + 2-deep register prefetch:
// ISSUE(t) runs TWO supersteps before BSTW(t) consumes it (two named banks,
// compile-time parity), so global-load latency is fully covered and BSTW
// never stalls on vmcnt. Everything else identical to R8.
// Volume [B=2][1][D=160][H=192][W=160] fp32. Window 9^3, zero-padded, /729.
// Tile TH=16 x TW=16, ZC=16 z-planes/chunk (NSTEP=24 planes touched).
// Superstep s:
//   P1: C(s): H-axis 9-tap hsum->vsum
//   P2: BSTW(s+1) [consume bank (s+1)&1] ; ISSUE(s+3) -> same bank ; D(s)
// Hazards (single-buffered, 2 barriers): as R8. Bank reuse is
// consume-then-refill within one phase (register dependencies order it).

#define NB 2
#define ND 160
#define NH 192
#define NW 160
#define TH 16
#define TW 16
#define ZC 16
#define ZCH 10             // 10*16 = 160
#define NSTEP (ZC + 8)     // 24 planes touched per chunk
#define NITER 36           // 2 blocks of 18 (static ring slot AND bank parity)
#define HROWS 25           // 24 used + 1 pad
#define HSTR 20            // 16 used + 4
#define VROWS 16
#define VSTR 20
#define NTH 256

__device__ __forceinline__ float4 f4add(float4 a, float4 b) {
    return make_float4(a.x + b.x, a.y + b.y, a.z + b.z, a.w + b.w);
}
__device__ __forceinline__ float4 f4sub(float4 a, float4 b) {
    return make_float4(a.x - b.x, a.y - b.y, a.z - b.z, a.w - b.w);
}

// Publish fence: drain own LDS writes, raw barrier. No vmcnt drain --
// in-flight global loads keep flying across the sync.
__device__ __forceinline__ void barw() {
    asm volatile("s_waitcnt lgkmcnt(0)" ::: "memory");
    __builtin_amdgcn_s_barrier();
    asm volatile("" ::: "memory");
}

__global__ __launch_bounds__(NTH) void ncc_main(
        const float* __restrict__ I, const float* __restrict__ J,
        double* __restrict__ gacc) {
    __shared__ float hsum[5][HROWS][HSTR];   // 10.0 KB
    __shared__ float vsum[5][VROWS][VSTR];   // 6.4 KB    total 16.4 KB
    __shared__ double wred[4];

    const int tid = threadIdx.x;
    const int tx = tid & 15;
    const int ty = tid >> 4;      // D: ty 0..15

    const int tileW = blockIdx.x % (NW / TW);          // 0..9
    const int tileH = blockIdx.x / (NW / TW);          // 0..11
    const int w0 = tileW * TW;
    const int h0 = tileH * TH;
    const int z0 = blockIdx.y * ZC;
    const size_t volBase = (size_t)blockIdx.z * ND * NH * NW;

    // ---- BSTW/ISSUE decode: 96 threads = 24 halo rows x 4 output-quads ----
    const bool bs_on = (tid < 96);
    const int br = tid >> 2;                // 0..23
    const int bq = tid & 3;                 // 0..3
    const int bh = h0 - 4 + br;
    const bool h_ok = bs_on && bh >= 0 && bh < NH;
    bool wok[3];
    int goff[3];
#pragma unroll
    for (int kk = 0; kk < 3; ++kk) {
        const int w = w0 - 4 + 4 * (bq + kk);
        wok[kk] = (w >= 0) && (w <= NW - 4);
        goff[kk] = bh * NW + w;
    }
    // two named prefetch banks (bank = plane index & 1)
    float4 g0I[3], g0J[3], g1I[3], g1J[3];
#pragma unroll
    for (int kk = 0; kk < 3; ++kk) {
        g0I[kk] = make_float4(0,0,0,0); g0J[kk] = g0I[kk];
        g1I[kk] = g0I[kk];               g1J[kk] = g0I[kk];
    }

    // ---- C decode: tid 96..175 (disjoint from BSTW): 5f x 4cg x 4strips ----
    const bool c_on = (tid >= 96) && (tid < 176);
    const int cix = c_on ? (tid - 96) : 0;
    const int cf = cix >> 4;                // 0..4
    const int ccg = cix & 3;                // 0..3
    const int cstrip = (cix >> 2) & 3;      // 0..3
    const int cr0 = cstrip << 2;
    const int cc0 = ccg << 2;
    const float* csrc = &hsum[cf][cr0][cc0];
    float* cdst = &vsum[cf][cr0][cc0];

// issue 6 global float4 loads for plane t into bank (GI,GJ) (no wait)
#define ISSUE_B(t, GI, GJ) do {                                                \
    const int zt_ = z0 - 4 + (t);                                              \
    const bool zok_ = (zt_ >= 0) && (zt_ < ND);                                \
    const size_t zb_ = volBase + (size_t)zt_ * (NH * NW);                      \
    _Pragma("unroll") for (int kk = 0; kk < 3; ++kk) {                         \
        GI[kk] = make_float4(0.f, 0.f, 0.f, 0.f); GJ[kk] = GI[kk];             \
        if (h_ok && zok_ && wok[kk]) {                                         \
            GI[kk] = *(const float4*)(I + zb_ + goff[kk]);                     \
            GJ[kk] = *(const float4*)(J + zb_ + goff[kk]);                     \
        }                                                                      \
    }                                                                          \
} while (0)

// sliding 9-sum over 12-value window -> 4 outputs, write hsum[F][br][4*bq]
#define BSLIDE(EXPR, F) do {                                                   \
    float s_ = EXPR(0);                                                        \
    _Pragma("unroll") for (int k_ = 1; k_ < 9; ++k_) s_ += EXPR(k_);           \
    float o_[4]; o_[0] = s_;                                                   \
    _Pragma("unroll") for (int j_ = 1; j_ < 4; ++j_) {                         \
        s_ += EXPR(j_ + 8) - EXPR(j_ - 1); o_[j_] = s_; }                      \
    *(float4*)&hsum[F][br][4 * bq] = *(float4*)&o_[0];                         \
} while (0)
#define E_I(k)  pI[k]
#define E_J(k)  pJ[k]
#define E_I2(k) (pI[k] * pI[k])
#define E_J2(k) (pJ[k] * pJ[k])
#define E_IJ(k) (pI[k] * pJ[k])

// consume bank (GI,GJ): products + W-axis sliding sums -> hsum (5 fields)
#define BSTW_B(GI, GJ) do { if (bs_on) {                                       \
    float pI[12], pJ[12];                                                      \
    _Pragma("unroll") for (int kk = 0; kk < 3; ++kk) {                         \
        *(float4*)&pI[4 * kk] = GI[kk];                                        \
        *(float4*)&pJ[4 * kk] = GJ[kk];                                        \
    }                                                                          \
    BSLIDE(E_I, 0); BSLIDE(E_J, 1); BSLIDE(E_I2, 2);                           \
    BSLIDE(E_J2, 3); BSLIDE(E_IJ, 4);                                          \
} } while (0)

// H-axis 9-tap sliding sums: 4-row strip, hsum -> vsum
#define DO_C() do { if (c_on) {                                                \
    float4 r0v = *(const float4*)(csrc + 0 * HSTR);                            \
    float4 r1v = *(const float4*)(csrc + 1 * HSTR);                            \
    float4 r2v = *(const float4*)(csrc + 2 * HSTR);                            \
    float4 s4 = f4add(f4add(r0v, r1v), r2v);                                   \
    _Pragma("unroll") for (int k = 3; k < 9; ++k)                              \
        s4 = f4add(s4, *(const float4*)(csrc + k * HSTR));                     \
    *(float4*)(cdst + 0 * VSTR) = s4;                                          \
    s4 = f4sub(f4add(s4, *(const float4*)(csrc +  9 * HSTR)), r0v);            \
    *(float4*)(cdst + 1 * VSTR) = s4;                                          \
    s4 = f4sub(f4add(s4, *(const float4*)(csrc + 10 * HSTR)), r1v);            \
    *(float4*)(cdst + 2 * VSTR) = s4;                                          \
    s4 = f4sub(f4add(s4, *(const float4*)(csrc + 11 * HSTR)), r2v);            \
    *(float4*)(cdst + 3 * VSTR) = s4;                                          \
} } while (0)

    float ring[5][9];
    float acc[5];
#pragma unroll
    for (int f = 0; f < 5; ++f) {
        acc[f] = 0.f;
#pragma unroll
        for (int k = 0; k < 9; ++k) ring[f][k] = 0.f;
    }
    float partial = 0.f;

    // ---- prologue: banks 0,1 filled; plane 0 staged; bank0 refilled (t=2) ----
    ISSUE_B(0, g0I, g0J);
    ISSUE_B(1, g1I, g1J);
    BSTW_B(g0I, g0J);          // plane 0 -> hsum
    ISSUE_B(2, g0I, g0J);
    barw();

#pragma unroll 1
    for (int ss = 0; ss < NITER; ss += 18) {
#pragma unroll
        for (int jj = 0; jj < 18; ++jj) {    // s = ss+jj; ss%18==0 so
            const int s = ss + jj;           // s%9 == jj%9, s&1 == jj&1 (static)
            if (s < NSTEP) {
                const int slot = jj % 9;     // ring slot of plane s
                const bool moreB = (s + 1 < NSTEP);
                const bool moreI = (s + 3 < NSTEP);

                // ---- P1: C(s) ----
                DO_C();
                barw();

                // ---- P2: BSTW(s+1) <- bank (s+1)&1 ; ISSUE(s+3) -> same bank ; D(s) ----
                if ((jj & 1) == 0) {         // (s+1)&1 == 1 : bank1
                    if (moreB) BSTW_B(g1I, g1J);
                    if (moreI) ISSUE_B(s + 3, g1I, g1J);
                } else {                     // bank0
                    if (moreB) BSTW_B(g0I, g0J);
                    if (moreI) ISSUE_B(s + 3, g0I, g0J);
                }
                {
#pragma unroll
                    for (int f = 0; f < 5; ++f) {
                        const float v = vsum[f][ty][tx];
                        acc[f] += v - ring[f][slot];
                        ring[f][slot] = v;
                    }
                    if (s >= 8) {
                        const float Is = acc[0], Js = acc[1];
                        const float I2 = acc[2], J2 = acc[3], IJ = acc[4];
                        const float inv = 1.0f / 729.0f;
                        const float uI = Is * inv, uJ = Js * inv;
                        const float cross = IJ - uJ * Is - uI * Js + uI * uJ * 729.0f;
                        const float Iv = I2 - 2.0f * uI * Is + uI * uI * 729.0f;
                        const float Jv = J2 - 2.0f * uJ * Js + uJ * uJ * 729.0f;
                        partial += cross * cross / (Iv * Jv + 1e-5f);
                    }
                }
                barw();
            }
        }
    }

    // ---------- reduction: wave shfl -> LDS -> one atomic per block ----------
    double dp = (double)partial;
#pragma unroll
    for (int off = 32; off > 0; off >>= 1)
        dp += __shfl_down(dp, off, 64);
    if ((tid & 63) == 0) wred[tid >> 6] = dp;
    __syncthreads();
    if (tid == 0) atomicAdd(gacc, wred[0] + wred[1] + wred[2] + wred[3]);
}

__global__ void ncc_fin(const double* __restrict__ gacc, float* __restrict__ out) {
    out[0] = (float)(-gacc[0] / (double)((long long)NB * ND * NH * NW));
}

extern "C" void kernel_launch(void* const* d_in, const int* in_sizes, int n_in,
                              void* d_out, int out_size, void* d_ws, size_t ws_size,
                              hipStream_t stream) {
    const float* I = (const float*)d_in[0];   // y_true
    const float* J = (const float*)d_in[1];   // y_pred
    double* ws = (double*)d_ws;

    hipMemsetAsync(d_ws, 0, sizeof(double), stream);   // graph-capture safe

    dim3 grid((NW / TW) * (NH / TH), ZCH, NB);         // 120 x 10 x 2 = 2400 blocks
    ncc_main<<<grid, NTH, 0, stream>>>(I, J, ws);
    ncc_fin<<<1, 1, 0, stream>>>(ws, (float*)d_out);
}

// Round 10
// 92.528 us; speedup vs baseline: 1.4132x; 1.1817x over previous
//
#include <hip/hip_runtime.h>

// NCC loss, fused single pass. R10 = R9 +
//  (1) 2-plane supersteps: 1 barrier/plane; P2 = BSTW+ISSUE+D keeps all lanes busy
//  (2) 8-output field-fused BSTW (window 16): per-output VALU nearly halved
//  (3) XCD-aware chunked blockIdx swizzle: tile's z-chunks + W-neighbors on one
//      XCD -> halo re-reads become L2 hits (per-XCD set ~1.6 MB < 4 MB L2)
//  (4) VSTR=24: D-phase vsum reads provably minimum-conflict (2 lanes/bank)
// Volume [B=2][1][D=160][H=192][W=160] fp32. Window 9^3, zero-padded, /729.
// Tile TH=16 x TW=16, ZC=16 planes/chunk (NSTEP=24 -> 12 supersteps of 2).
// Superstep s (planes 2s, 2s+1):
//   P1: C(s): H-axis 9-tap hsum->vsum (both planes)            | barrier
//   P2: BSTW(s+1) consume reg bank -> hsum; ISSUE(s+2) refill bank (register-
//       ordered after consume); D(s): z-ring + cc (both planes) | barrier
// Hazards (single-buffered): hsum w P2(s) -> r P1(s+1): 1 bar; WAR C(s) r ->
// BSTW(s+1) w (P1->P2): 1 bar; vsum w P1(s) -> r P2(s): 1 bar; WAR D(s) r ->
// C(s+1) w: 1 bar. Bank: consume-then-refill in one phase (reg deps order it).

#define NB 2
#define ND 160
#define NH 192
#define NW 160
#define TH 16
#define TW 16
#define ZC 16
#define ZCH 10
#define NSTEP (ZC + 8)      // 24 planes per chunk
#define NSUP (NSTEP / 2)    // 12 supersteps
#define NGRID 2400          // 120 tiles x 10 zchunks x 2 batches
#define CPX (NGRID / 8)     // 300 blocks per XCD chunk
#define HROWS 25            // 24 used + pad
#define HSTR 20             // 16 used + 4
#define VROWS 17
#define VSTR 24             // D reads: rows 0,24,48,72 %32 -> each bank 2x (min)
#define VFSTR (VROWS * VSTR)
#define NTH 256

__device__ __forceinline__ float4 f4add(float4 a, float4 b) {
    return make_float4(a.x + b.x, a.y + b.y, a.z + b.z, a.w + b.w);
}
__device__ __forceinline__ float4 f4sub(float4 a, float4 b) {
    return make_float4(a.x - b.x, a.y - b.y, a.z - b.z, a.w - b.w);
}

// Publish fence: drain own LDS writes, raw barrier. No vmcnt drain --
// in-flight global loads keep flying across the sync.
__device__ __forceinline__ void barw() {
    asm volatile("s_waitcnt lgkmcnt(0)" ::: "memory");
    __builtin_amdgcn_s_barrier();
    asm volatile("" ::: "memory");
}

__global__ __launch_bounds__(NTH) void ncc_main(
        const float* __restrict__ I, const float* __restrict__ J,
        double* __restrict__ gacc) {
    __shared__ float hsum[2][5][HROWS][HSTR];   // 20.0 KB (2 planes)
    __shared__ float vsum[2][5][VROWS][VSTR];   // 16.3 KB
    __shared__ double wred[4];

    const int tid = threadIdx.x;
    const int tx = tid & 15;
    const int ty = tid >> 4;           // 0..15

    // ---- XCD-aware chunked swizzle (bijective: NGRID % 8 == 0) ----
    const int bid = blockIdx.x;
    const int nid = (bid & 7) * CPX + (bid >> 3);
    const int tile = nid / 20;          // 20 consecutive nids = one tile's (zc,b)
    const int rem = nid - tile * 20;
    const int zci = rem >> 1;
    const int bb = rem & 1;
    const int tileW = tile % 10;
    const int tileH = tile / 10;
    const int w0 = tileW * TW;
    const int h0 = tileH * TH;
    const int z0 = zci * ZC;
    const size_t volBase = (size_t)bb * ND * NH * NW;

    // ---- BSTW/ISSUE decode: 96 threads = 2 planes x (24 rows x 2 octs) ----
    const bool bs_on = (tid < 96);
    const int bp = (bs_on && tid >= 48) ? 1 : 0;   // plane parity in superstep
    const int b2 = bs_on ? (tid - bp * 48) : 0;
    const int br = b2 >> 1;             // 0..23 halo row
    const int bo = b2 & 1;              // oct: outputs 8bo..8bo+7
    const int bh = h0 - 4 + br;
    const bool h_ok = bs_on && bh >= 0 && bh < NH;
    bool wok[4];
    int goff[4];
#pragma unroll
    for (int kk = 0; kk < 4; ++kk) {
        const int w = w0 - 4 + 8 * bo + 4 * kk;   // window cols 8bo-4..8bo+11
        wok[kk] = (w >= 0) && (w <= NW - 4);
        goff[kk] = bh * NW + w;
    }
    // register bank: 16-col raw window for both fields (consumed in place)
    float bI[16], bJ[16];
#pragma unroll
    for (int k = 0; k < 4; ++k) {
        *(float4*)&bI[4 * k] = make_float4(0.f, 0.f, 0.f, 0.f);
        *(float4*)&bJ[4 * k] = make_float4(0.f, 0.f, 0.f, 0.f);
    }

    // ---- C decode: tid 96..255 = 2 planes x (5f x 4 colgrp x 4 strips) ----
    const bool c_on = (tid >= 96);
    const int cix = c_on ? (tid - 96) : 0;   // 0..159
    const int cp = (cix >= 80) ? 1 : 0;
    const int c2 = cix - cp * 80;
    const int cf = c2 >> 4;
    const int cstrip = (c2 >> 2) & 3;
    const int ccg = c2 & 3;
    const int cr0 = cstrip << 2;
    const int cc0 = ccg << 2;
    const float* csrc = &hsum[cp][cf][cr0][cc0];
    float* cdst = &vsum[cp][cf][cr0][cc0];

// issue 8 global float4 loads (4 I + 4 J) for superstep t, plane bp (no wait)
#define ISSUE(t) do {                                                          \
    const int zt_ = z0 - 4 + 2 * (t) + bp;                                     \
    const bool zok_ = (zt_ >= 0) && (zt_ < ND);                                \
    const size_t zb_ = volBase + (size_t)zt_ * (NH * NW);                      \
    _Pragma("unroll") for (int kk = 0; kk < 4; ++kk) {                         \
        *(float4*)&bI[4 * kk] = make_float4(0.f, 0.f, 0.f, 0.f);               \
        *(float4*)&bJ[4 * kk] = make_float4(0.f, 0.f, 0.f, 0.f);               \
        if (h_ok && zok_ && wok[kk]) {                                         \
            *(float4*)&bI[4 * kk] = *(const float4*)(I + zb_ + goff[kk]);      \
            *(float4*)&bJ[4 * kk] = *(const float4*)(J + zb_ + goff[kk]);      \
        }                                                                      \
    }                                                                          \
} while (0)

// sliding 9-sum over 16-value window -> 8 outputs, write hsum[bp][F][br][8bo]
#define BSLIDE(EXPR, F) do {                                                   \
    float s_ = EXPR(0);                                                        \
    _Pragma("unroll") for (int k_ = 1; k_ < 9; ++k_) s_ += EXPR(k_);           \
    float o_[8]; o_[0] = s_;                                                   \
    _Pragma("unroll") for (int j_ = 1; j_ < 8; ++j_) {                         \
        s_ += EXPR(j_ + 8) - EXPR(j_ - 1); o_[j_] = s_; }                      \
    *(float4*)&hsum[bp][F][br][8 * bo]     = *(float4*)&o_[0];                 \
    *(float4*)&hsum[bp][F][br][8 * bo + 4] = *(float4*)&o_[4];                 \
} while (0)
#define E_I(k)  bI[k]
#define E_J(k)  bJ[k]
#define E_I2(k) (bI[k] * bI[k])
#define E_J2(k) (bJ[k] * bJ[k])
#define E_IJ(k) (bI[k] * bJ[k])

// consume bank: products + W-axis sliding sums -> hsum (5 fields, 8 outputs)
#define BSTW() do { if (bs_on) {                                               \
    BSLIDE(E_I, 0); BSLIDE(E_J, 1); BSLIDE(E_I2, 2);                           \
    BSLIDE(E_J2, 3); BSLIDE(E_IJ, 4);                                          \
} } while (0)

// H-axis 9-tap sliding sums: 4-row strip, hsum[cp] -> vsum[cp]
#define DO_C() do { if (c_on) {                                                \
    float4 r0v = *(const float4*)(csrc + 0 * HSTR);                            \
    float4 r1v = *(const float4*)(csrc + 1 * HSTR);                            \
    float4 r2v = *(const float4*)(csrc + 2 * HSTR);                            \
    float4 s4 = f4add(f4add(r0v, r1v), r2v);                                   \
    _Pragma("unroll") for (int k = 3; k < 9; ++k)                              \
        s4 = f4add(s4, *(const float4*)(csrc + k * HSTR));                     \
    *(float4*)(cdst + 0 * VSTR) = s4;                                          \
    s4 = f4sub(f4add(s4, *(const float4*)(csrc +  9 * HSTR)), r0v);            \
    *(float4*)(cdst + 1 * VSTR) = s4;                                          \
    s4 = f4sub(f4add(s4, *(const float4*)(csrc + 10 * HSTR)), r1v);            \
    *(float4*)(cdst + 2 * VSTR) = s4;                                          \
    s4 = f4sub(f4add(s4, *(const float4*)(csrc + 11 * HSTR)), r2v);            \
    *(float4*)(cdst + 3 * VSTR) = s4;                                          \
} } while (0)

// D: z-ring + cc epilogue for one plane (PL buffer index, SLOT ring slot,
// IDX = absolute plane index within chunk, compile-time per unrolled jj)
#define DO_D(PL, SLOT, IDX) do {                                               \
    const float* vbase_ = &vsum[PL][0][ty][tx];                                \
    _Pragma("unroll") for (int f = 0; f < 5; ++f) {                            \
        const float v = vbase_[f * VFSTR];                                     \
        acc[f] += v - ring[f][SLOT];                                           \
        ring[f][SLOT] = v;                                                     \
    }                                                                          \
    if ((IDX) >= 8) {                                                          \
        const float Is = acc[0], Js = acc[1];                                  \
        const float I2 = acc[2], J2 = acc[3], IJ = acc[4];                     \
        const float inv = 1.0f / 729.0f;                                       \
        const float uI = Is * inv, uJ = Js * inv;                              \
        const float cross = IJ - uJ * Is - uI * Js + uI * uJ * 729.0f;         \
        const float Iv = I2 - 2.0f * uI * Is + uI * uI * 729.0f;               \
        const float Jv = J2 - 2.0f * uJ * Js + uJ * uJ * 729.0f;               \
        partial += cross * cross / (Iv * Jv + 1e-5f);                          \
    }                                                                          \
} while (0)

    float ring[5][9];
    float acc[5];
#pragma unroll
    for (int f = 0; f < 5; ++f) {
        acc[f] = 0.f;
#pragma unroll
        for (int k = 0; k < 9; ++k) ring[f][k] = 0.f;
    }
    float partial = 0.f;

    // ---- prologue: superstep 0 staged into hsum; bank refilled for ss 1 ----
    ISSUE(0);
    BSTW();          // waits vmcnt for ISSUE(0) loads (once)
    ISSUE(1);
    barw();

#pragma unroll 1
    for (int ss = 0; ss < 18; ss += 9) {
#pragma unroll
        for (int jj = 0; jj < 9; ++jj) {
            const int s = ss + jj;        // (2s+p) % 9 == (2jj+p) % 9: static
            if (s < NSUP) {
                // ---- P1: C(s) ----
                DO_C();
                barw();

                // ---- P2: BSTW(s+1) <- bank ; ISSUE(s+2) -> bank ; D(s) ----
                if (s + 1 < NSUP) BSTW();
                if (s + 2 < NSUP) ISSUE(s + 2);
                DO_D(0, (2 * jj) % 9, 2 * s);
                DO_D(1, (2 * jj + 1) % 9, 2 * s + 1);
                barw();
            }
        }
    }

    // ---------- reduction: wave shfl -> LDS -> one atomic per block ----------
    double dp = (double)partial;
#pragma unroll
    for (int off = 32; off > 0; off >>= 1)
        dp += __shfl_down(dp, off, 64);
    if ((tid & 63) == 0) wred[tid >> 6] = dp;
    __syncthreads();
    if (tid == 0) atomicAdd(gacc, wred[0] + wred[1] + wred[2] + wred[3]);
}

__global__ void ncc_fin(const double* __restrict__ gacc, float* __restrict__ out) {
    out[0] = (float)(-gacc[0] / (double)((long long)NB * ND * NH * NW));
}

extern "C" void kernel_launch(void* const* d_in, const int* in_sizes, int n_in,
                              void* d_out, int out_size, void* d_ws, size_t ws_size,
                              hipStream_t stream) {
    const float* I = (const float*)d_in[0];   // y_true
    const float* J = (const float*)d_in[1];   // y_pred
    double* ws = (double*)d_ws;

    hipMemsetAsync(d_ws, 0, sizeof(double), stream);   // graph-capture safe

    ncc_main<<<dim3(NGRID), NTH, 0, stream>>>(I, J, ws);   // 1D swizzled grid
    ncc_fin<<<1, 1, 0, stream>>>(ws, (float*)d_out);
}

// Round 11
// 91.506 us; speedup vs baseline: 1.4290x; 1.0112x over previous
//
#include <hip/hip_runtime.h>

// NCC loss, fused single pass. R11 = R10 +
//  (1) ZC 16->32: z-halo compute redundancy 1.5x -> 1.25x (-17% all-pipe work);
//      grid 1200 = 8*150, XCD swizzle stays bijective
//  (2) hsum XOR swizzle (col ^= ((row>>3)&3)<<2 on float4 base): BSTW's 3-way
//      write conflict (rows r,r+8,r+16 alias at HSTR=20) -> conflict-free
//  (3) otherwise identical to R10 (roles, reg prefetch bank, 2-barrier superstep)
// Volume [B=2][1][D=160][H=192][W=160] fp32. Window 9^3, zero-padded, /729.
// Tile TH=16 x TW=16, ZC=32 planes/chunk (NSTEP=40 -> 20 supersteps of 2).
// Superstep s (planes 2s, 2s+1):
//   P1: C(s): H-axis 9-tap hsum->vsum (both planes)            | barrier
//   P2: BSTW(s+1) consume reg bank -> hsum; ISSUE(s+2) refill bank; D(s) | barrier

#define NB 2
#define ND 160
#define NH 192
#define NW 160
#define TH 16
#define TW 16
#define ZC 32
#define NSTEP (ZC + 8)      // 40 planes per chunk
#define NSUP (NSTEP / 2)    // 20 supersteps
#define NGRID 1200          // 120 tiles x 5 zchunks x 2 batches
#define CPX (NGRID / 8)     // 150 blocks per XCD chunk
#define HROWS 25            // 24 used + pad
#define HSTR 20             // 16 used + 4
#define VROWS 17
#define VSTR 24             // D reads: 2 lanes/bank (free per m136)
#define VFSTR (VROWS * VSTR)
#define NTH 256

// XOR swizzle on hsum float4 col-base (bits 2-3) by row octave: bijective
// within [0,16), spreads rows r, r+8, r+16 (same bank base at HSTR=20) apart.
#define HSWZ(r) ((((r) >> 3) & 3) << 2)

__device__ __forceinline__ float4 f4add(float4 a, float4 b) {
    return make_float4(a.x + b.x, a.y + b.y, a.z + b.z, a.w + b.w);
}
__device__ __forceinline__ float4 f4sub(float4 a, float4 b) {
    return make_float4(a.x - b.x, a.y - b.y, a.z - b.z, a.w - b.w);
}

// Publish fence: drain own LDS writes, raw barrier. No vmcnt drain.
__device__ __forceinline__ void barw() {
    asm volatile("s_waitcnt lgkmcnt(0)" ::: "memory");
    __builtin_amdgcn_s_barrier();
    asm volatile("" ::: "memory");
}

__global__ __launch_bounds__(NTH) void ncc_main(
        const float* __restrict__ I, const float* __restrict__ J,
        double* __restrict__ gacc) {
    __shared__ float hsum[2][5][HROWS][HSTR];   // 20.0 KB (2 planes)
    __shared__ float vsum[2][5][VROWS][VSTR];   // 16.3 KB
    __shared__ double wred[4];

    const int tid = threadIdx.x;
    const int tx = tid & 15;
    const int ty = tid >> 4;           // 0..15

    // ---- XCD-aware chunked swizzle (bijective: NGRID % 8 == 0) ----
    const int bid = blockIdx.x;
    const int nid = (bid & 7) * CPX + (bid >> 3);
    const int tile = nid / 10;          // 10 consecutive nids = one tile's (zc,b)
    const int rem = nid - tile * 10;
    const int zci = rem >> 1;           // 0..4
    const int bb = rem & 1;
    const int tileW = tile % 10;
    const int tileH = tile / 10;
    const int w0 = tileW * TW;
    const int h0 = tileH * TH;
    const int z0 = zci * ZC;
    const size_t volBase = (size_t)bb * ND * NH * NW;

    // ---- BSTW/ISSUE decode: 96 threads = 2 planes x (24 rows x 2 octs) ----
    const bool bs_on = (tid < 96);
    const int bp = (bs_on && tid >= 48) ? 1 : 0;   // plane parity in superstep
    const int b2 = bs_on ? (tid - bp * 48) : 0;
    const int br = b2 >> 1;             // 0..23 halo row
    const int bo = b2 & 1;              // oct: outputs 8bo..8bo+7
    const int bh = h0 - 4 + br;
    const bool h_ok = bs_on && bh >= 0 && bh < NH;
    bool wok[4];
    int goff[4];
#pragma unroll
    for (int kk = 0; kk < 4; ++kk) {
        const int w = w0 - 4 + 8 * bo + 4 * kk;   // window cols 8bo-4..8bo+11
        wok[kk] = (w >= 0) && (w <= NW - 4);
        goff[kk] = bh * NW + w;
    }
    // register bank: 16-col raw window for both fields (consumed in place)
    float bI[16], bJ[16];
#pragma unroll
    for (int k = 0; k < 4; ++k) {
        *(float4*)&bI[4 * k] = make_float4(0.f, 0.f, 0.f, 0.f);
        *(float4*)&bJ[4 * k] = make_float4(0.f, 0.f, 0.f, 0.f);
    }

    // ---- C decode: tid 96..255 = 2 planes x (5f x 4 colgrp x 4 strips) ----
    const bool c_on = (tid >= 96);
    const int cix = c_on ? (tid - 96) : 0;   // 0..159
    const int cp = (cix >= 80) ? 1 : 0;
    const int c2 = cix - cp * 80;
    const int cf = c2 >> 4;
    const int cstrip = (c2 >> 2) & 3;
    const int ccg = c2 & 3;
    const int cr0 = cstrip << 2;
    const int cc0 = ccg << 2;
    float* cdst = &vsum[cp][cf][cr0][cc0];

// issue 8 global float4 loads (4 I + 4 J) for superstep t, plane bp (no wait)
#define ISSUE(t) do {                                                          \
    const int zt_ = z0 - 4 + 2 * (t) + bp;                                     \
    const bool zok_ = (zt_ >= 0) && (zt_ < ND);                                \
    const size_t zb_ = volBase + (size_t)zt_ * (NH * NW);                      \
    _Pragma("unroll") for (int kk = 0; kk < 4; ++kk) {                         \
        *(float4*)&bI[4 * kk] = make_float4(0.f, 0.f, 0.f, 0.f);               \
        *(float4*)&bJ[4 * kk] = make_float4(0.f, 0.f, 0.f, 0.f);               \
        if (h_ok && zok_ && wok[kk]) {                                         \
            *(float4*)&bI[4 * kk] = *(const float4*)(I + zb_ + goff[kk]);      \
            *(float4*)&bJ[4 * kk] = *(const float4*)(J + zb_ + goff[kk]);      \
        }                                                                      \
    }                                                                          \
} while (0)

// sliding 9-sum over 16-value window -> 8 outputs, write hsum (swizzled cols)
#define BSLIDE(EXPR, F) do {                                                   \
    float s_ = EXPR(0);                                                        \
    _Pragma("unroll") for (int k_ = 1; k_ < 9; ++k_) s_ += EXPR(k_);           \
    float o_[8]; o_[0] = s_;                                                   \
    _Pragma("unroll") for (int j_ = 1; j_ < 8; ++j_) {                         \
        s_ += EXPR(j_ + 8) - EXPR(j_ - 1); o_[j_] = s_; }                      \
    *(float4*)&hsum[bp][F][br][(8 * bo) ^ HSWZ(br)]     = *(float4*)&o_[0];    \
    *(float4*)&hsum[bp][F][br][(8 * bo + 4) ^ HSWZ(br)] = *(float4*)&o_[4];    \
} while (0)
#define E_I(k)  bI[k]
#define E_J(k)  bJ[k]
#define E_I2(k) (bI[k] * bI[k])
#define E_J2(k) (bJ[k] * bJ[k])
#define E_IJ(k) (bI[k] * bJ[k])

// consume bank: products + W-axis sliding sums -> hsum (5 fields, 8 outputs)
#define BSTW() do { if (bs_on) {                                               \
    BSLIDE(E_I, 0); BSLIDE(E_J, 1); BSLIDE(E_I2, 2);                           \
    BSLIDE(E_J2, 3); BSLIDE(E_IJ, 4);                                          \
} } while (0)

// swizzled hsum read: row r, col-quad base cc0
#define CRD(r) (*(const float4*)&hsum[cp][cf][r][cc0 ^ HSWZ(r)])

// H-axis 9-tap sliding sums: 4-row strip, hsum[cp] -> vsum[cp]
#define DO_C() do { if (c_on) {                                                \
    float4 r0v = CRD(cr0 + 0);                                                 \
    float4 r1v = CRD(cr0 + 1);                                                 \
    float4 r2v = CRD(cr0 + 2);                                                 \
    float4 s4 = f4add(f4add(r0v, r1v), r2v);                                   \
    _Pragma("unroll") for (int k = 3; k < 9; ++k)                              \
        s4 = f4add(s4, CRD(cr0 + k));                                          \
    *(float4*)(cdst + 0 * VSTR) = s4;                                          \
    s4 = f4sub(f4add(s4, CRD(cr0 +  9)), r0v);                                 \
    *(float4*)(cdst + 1 * VSTR) = s4;                                          \
    s4 = f4sub(f4add(s4, CRD(cr0 + 10)), r1v);                                 \
    *(float4*)(cdst + 2 * VSTR) = s4;                                          \
    s4 = f4sub(f4add(s4, CRD(cr0 + 11)), r2v);                                 \
    *(float4*)(cdst + 3 * VSTR) = s4;                                          \
} } while (0)

// D: z-ring + cc epilogue for one plane
#define DO_D(PL, SLOT, IDX) do {                                               \
    const float* vbase_ = &vsum[PL][0][ty][tx];                                \
    _Pragma("unroll") for (int f = 0; f < 5; ++f) {                            \
        const float v = vbase_[f * VFSTR];                                     \
        acc[f] += v - ring[f][SLOT];                                           \
        ring[f][SLOT] = v;                                                     \
    }                                                                          \
    if ((IDX) >= 8) {                                                          \
        const float Is = acc[0], Js = acc[1];                                  \
        const float I2 = acc[2], J2 = acc[3], IJ = acc[4];                     \
        const float inv = 1.0f / 729.0f;                                       \
        const float uI = Is * inv, uJ = Js * inv;                              \
        const float cross = IJ - uJ * Is - uI * Js + uI * uJ * 729.0f;         \
        const float Iv = I2 - 2.0f * uI * Is + uI * uI * 729.0f;               \
        const float Jv = J2 - 2.0f * uJ * Js + uJ * uJ * 729.0f;               \
        partial += cross * cross / (Iv * Jv + 1e-5f);                          \
    }                                                                          \
} while (0)

    float ring[5][9];
    float acc[5];
#pragma unroll
    for (int f = 0; f < 5; ++f) {
        acc[f] = 0.f;
#pragma unroll
        for (int k = 0; k < 9; ++k) ring[f][k] = 0.f;
    }
    float partial = 0.f;

    // ---- prologue: superstep 0 staged into hsum; bank refilled for ss 1 ----
    ISSUE(0);
    BSTW();          // waits vmcnt for ISSUE(0) loads (once)
    ISSUE(1);
    barw();

#pragma unroll 1
    for (int ss = 0; ss < 27; ss += 9) {
#pragma unroll
        for (int jj = 0; jj < 9; ++jj) {
            const int s = ss + jj;        // (2s+p) % 9 == (2jj+p) % 9: static
            if (s < NSUP) {
                // ---- P1: C(s) ----
                DO_C();
                barw();

                // ---- P2: BSTW(s+1) <- bank ; ISSUE(s+2) -> bank ; D(s) ----
                if (s + 1 < NSUP) BSTW();
                if (s + 2 < NSUP) ISSUE(s + 2);
                DO_D(0, (2 * jj) % 9, 2 * s);
                DO_D(1, (2 * jj + 1) % 9, 2 * s + 1);
                barw();
            }
        }
    }

    // ---------- reduction: wave shfl -> LDS -> one atomic per block ----------
    double dp = (double)partial;
#pragma unroll
    for (int off = 32; off > 0; off >>= 1)
        dp += __shfl_down(dp, off, 64);
    if ((tid & 63) == 0) wred[tid >> 6] = dp;
    __syncthreads();
    if (tid == 0) atomicAdd(gacc, wred[0] + wred[1] + wred[2] + wred[3]);
}

__global__ void ncc_fin(const double* __restrict__ gacc, float* __restrict__ out) {
    out[0] = (float)(-gacc[0] / (double)((long long)NB * ND * NH * NW));
}

extern "C" void kernel_launch(void* const* d_in, const int* in_sizes, int n_in,
                              void* d_out, int out_size, void* d_ws, size_t ws_size,
                              hipStream_t stream) {
    const float* I = (const float*)d_in[0];   // y_true
    const float* J = (const float*)d_in[1];   // y_pred
    double* ws = (double*)d_ws;

    hipMemsetAsync(d_ws, 0, sizeof(double), stream);   // graph-capture safe

    ncc_main<<<dim3(NGRID), NTH, 0, stream>>>(I, J, ws);   // 1D swizzled grid
    ncc_fin<<<1, 1, 0, stream>>>(ws, (float*)d_out);
}